// Round 5
// baseline (886.630 us; speedup 1.0000x reference)
//
#include <hip/hip_runtime.h>
#include <cstdint>
#include <cstddef>

// SAGE 3-layer GNN, MI355X gfx950 — round 8:
//  * GEMM: gemm_stream — NO LDS, NO barriers. W (128KB, L2-resident) is
//    streamed per-wave straight to VGPRs in slot-order (coalesced 256B
//    segments); K-loop is pure loads+MFMA so the compiler can software-
//    pipeline freely. Previous LDS variants serialized on the
//    __syncthreads() vmcnt(0) drain every K-chunk (suspected ~100 µs each;
//    traffic floor is ~30 µs).
//  * aggregate: round-4 form (measured floor 114 µs, compulsory-miss-bound).
//  * prep_all fusion, slot-order W transpose, 4-pass fill_csr kept.

#define N_NODES 100000
#define N_EDGES 1600000

#define SCAN_BLOCKS 256
#define SCAN_T 256
#define FILL_PASSES 4

typedef unsigned short ushort;
typedef unsigned int uint;
typedef __attribute__((ext_vector_type(8))) short short8;
typedef __attribute__((ext_vector_type(4))) float floatx4;

#define AS1 __attribute__((address_space(1)))
#define AS3 __attribute__((address_space(3)))

__device__ __forceinline__ float bf2f(ushort h) {
    union { uint u; float f; } c; c.u = ((uint)h) << 16; return c.f;
}
__device__ __forceinline__ ushort f2bf(float f) {
    union { float f; uint u; } c; c.f = f;
    uint u = c.u;
    return (ushort)((u + 0x7FFFu + ((u >> 16) & 1u)) >> 16);  // RTNE
}

// ---------------- fused prep: count_edges + convert_x + 6 W transposes ----
// W [K,256] f32 -> Wt in slot order: elem i = ((q*256 + col)*8 + e),
// k = q*8 + e. A b-frag load then reads 16B/lane, 256B-contiguous per
// 16-lane group.

#define N4X (N_NODES * 128 / 4)

__global__ void prep_all(
    const int* __restrict__ dst, int* __restrict__ cnt,
    const float* __restrict__ x, ushort* __restrict__ xb,
    const float* __restrict__ Wl0, ushort* __restrict__ Wl0t,
    const float* __restrict__ Wr0, ushort* __restrict__ Wr0t,
    const float* __restrict__ Wl1, ushort* __restrict__ Wl1t,
    const float* __restrict__ Wr1, ushort* __restrict__ Wr1t,
    const float* __restrict__ Wl2, ushort* __restrict__ Wl2t,
    const float* __restrict__ Wr2, ushort* __restrict__ Wr2t)
{
    int i = blockIdx.x * blockDim.x + threadIdx.x;
    if (i < N_EDGES) { atomicAdd(&cnt[dst[i]], 1); return; }
    i -= N_EDGES;
    if (i < N4X) {
        float4 v = *(const float4*)&x[(size_t)i * 4];
        ushort4 o;
        o.x = f2bf(v.x); o.y = f2bf(v.y); o.z = f2bf(v.z); o.w = f2bf(v.w);
        *(ushort4*)&xb[(size_t)i * 4] = o;
        return;
    }
    i -= N4X;
#define WT2(Wsrc, Wdst, LIM) \
    if (i < (LIM)) { \
        int q = i >> 11, col = (i >> 3) & 255, e = i & 7; \
        Wdst[i] = f2bf(Wsrc[(q * 8 + e) * 256 + col]); \
        return; \
    } \
    i -= (LIM);
    WT2(Wl0, Wl0t, 32768)
    WT2(Wr0, Wr0t, 32768)
    WT2(Wl1, Wl1t, 65536)
    WT2(Wr1, Wr1t, 65536)
    WT2(Wl2, Wl2t, 65536)
    WT2(Wr2, Wr2t, 65536)
#undef WT2
}

// ---------------- CSR scan ----------------

__global__ __launch_bounds__(SCAN_T) void scan_partial(
    const int* __restrict__ cnt, int* __restrict__ bsum, int n)
{
    int chunk = (n + SCAN_BLOCKS - 1) / SCAN_BLOCKS;
    int beg = blockIdx.x * chunk;
    int end = beg + chunk; if (end > n) end = n;
    int t = threadIdx.x;
    int s = 0;
    for (int i = beg + t; i < end; i += SCAN_T) s += cnt[i];
    __shared__ int sh[SCAN_T];
    sh[t] = s;
    __syncthreads();
    for (int off = SCAN_T / 2; off > 0; off >>= 1) {
        if (t < off) sh[t] += sh[t + off];
        __syncthreads();
    }
    if (t == 0) bsum[blockIdx.x] = sh[0];
}

__global__ __launch_bounds__(SCAN_T) void scan_block_sums(int* __restrict__ bsum) {
    int t = threadIdx.x;
    __shared__ int sh[SCAN_T];
    int v = bsum[t];
    sh[t] = v;
    __syncthreads();
    for (int off = 1; off < SCAN_T; off <<= 1) {
        int u = (t >= off) ? sh[t - off] : 0;
        __syncthreads();
        sh[t] += u;
        __syncthreads();
    }
    bsum[t] = sh[t] - v;  // exclusive
}

__global__ __launch_bounds__(SCAN_T) void scan_fill(
    int* __restrict__ cnt, const int* __restrict__ bsum,
    int* __restrict__ row_ptr, int n)
{
    int chunk = (n + SCAN_BLOCKS - 1) / SCAN_BLOCKS;
    int beg = blockIdx.x * chunk;
    int end = beg + chunk; if (end > n) end = n;
    int t = threadIdx.x;
    int per = (chunk + SCAN_T - 1) / SCAN_T;
    int tb = beg + t * per;
    int te = tb + per; if (te > end) te = end;
    int s = 0;
    for (int i = tb; i < te; ++i) s += cnt[i];
    __shared__ int sh[SCAN_T];
    sh[t] = s;
    __syncthreads();
    for (int off = 1; off < SCAN_T; off <<= 1) {
        int u = (t >= off) ? sh[t - off] : 0;
        __syncthreads();
        sh[t] += u;
        __syncthreads();
    }
    int running = bsum[blockIdx.x] + sh[t] - s;
    for (int i = tb; i < te; ++i) {
        int c = cnt[i];
        row_ptr[i] = running;
        cnt[i] = running;  // becomes fill cursor
        running += c;
    }
    if (blockIdx.x == 0 && t == 0) row_ptr[n] = N_EDGES;
}

// 4 dst-range passes: per-pass dirty col_idx region (~1.6MB) stays L2-resident.
__global__ void fill_csr(const int* __restrict__ src, const int* __restrict__ dst,
                         int* __restrict__ cursor, int* __restrict__ col_idx) {
    int i = blockIdx.x * blockDim.x + threadIdx.x;
    if (i >= N_EDGES) return;
    int lo = (int)blockIdx.y * (N_NODES / FILL_PASSES);
    int hi = lo + (N_NODES / FILL_PASSES);
    int d = dst[i];
    if (d >= lo && d < hi) {
        int p = atomicAdd(&cursor[d], 1);
        col_idx[p] = src[i];
    }
}

// ---------------- mean aggregation (round-4 form, measured floor) ---------
__global__ __launch_bounds__(64) void aggregate_bf16(
    const ushort* __restrict__ xb, const int* __restrict__ row_ptr,
    const int* __restrict__ col_idx, ushort* __restrict__ outb, int F)
{
    int node = blockIdx.x;
    int t = threadIdx.x;
    int b = row_ptr[node], e = row_ptr[node + 1];
    float d = (float)(e - b); if (d < 1.f) d = 1.f;
    float inv = 1.f / d;

    if (F == 256) {
        int c = t * 4;
        float a0 = 0.f, a1 = 0.f, a2 = 0.f, a3 = 0.f;
        float b0 = 0.f, b1 = 0.f, b2 = 0.f, b3 = 0.f;
        int i = b;
        for (; i + 1 < e; i += 2) {
            int s0 = col_idx[i];
            int s1 = col_idx[i + 1];
            uint2 v0 = *(const uint2*)&xb[(size_t)s0 * 256 + c];
            uint2 v1 = *(const uint2*)&xb[(size_t)s1 * 256 + c];
            a0 += bf2f((ushort)(v0.x & 0xffff)); a1 += bf2f((ushort)(v0.x >> 16));
            a2 += bf2f((ushort)(v0.y & 0xffff)); a3 += bf2f((ushort)(v0.y >> 16));
            b0 += bf2f((ushort)(v1.x & 0xffff)); b1 += bf2f((ushort)(v1.x >> 16));
            b2 += bf2f((ushort)(v1.y & 0xffff)); b3 += bf2f((ushort)(v1.y >> 16));
        }
        if (i < e) {
            int s0 = col_idx[i];
            uint2 v0 = *(const uint2*)&xb[(size_t)s0 * 256 + c];
            a0 += bf2f((ushort)(v0.x & 0xffff)); a1 += bf2f((ushort)(v0.x >> 16));
            a2 += bf2f((ushort)(v0.y & 0xffff)); a3 += bf2f((ushort)(v0.y >> 16));
        }
        ushort4 o;
        o.x = f2bf((a0 + b0) * inv); o.y = f2bf((a1 + b1) * inv);
        o.z = f2bf((a2 + b2) * inv); o.w = f2bf((a3 + b3) * inv);
        *(ushort4*)&outb[(size_t)node * 256 + c] = o;
    } else {
        int c = t * 2;
        float a0 = 0.f, a1 = 0.f, b0 = 0.f, b1 = 0.f;
        int i = b;
        for (; i + 1 < e; i += 2) {
            int s0 = col_idx[i];
            int s1 = col_idx[i + 1];
            uint v0 = *(const uint*)&xb[(size_t)s0 * 128 + c];
            uint v1 = *(const uint*)&xb[(size_t)s1 * 128 + c];
            a0 += bf2f((ushort)(v0 & 0xffff)); a1 += bf2f((ushort)(v0 >> 16));
            b0 += bf2f((ushort)(v1 & 0xffff)); b1 += bf2f((ushort)(v1 >> 16));
        }
        if (i < e) {
            int s0 = col_idx[i];
            uint v0 = *(const uint*)&xb[(size_t)s0 * 128 + c];
            a0 += bf2f((ushort)(v0 & 0xffff)); a1 += bf2f((ushort)(v0 >> 16));
        }
        ushort2 o;
        o.x = f2bf((a0 + b0) * inv); o.y = f2bf((a1 + b1) * inv);
        *(ushort2*)&outb[(size_t)node * 128 + c] = o;
    }
}

// ---------------- streaming dual MFMA GEMM (no LDS, no barriers) ----------
// C[M,256] = relu?( A1[M,K]@W1 + A2[M,K]@W2 + bias ).
// 256 thr (4 waves), tile 128 rows x 256 cols. Wave w owns rows
// [row0+w*32, +32). B-frags streamed per-wave from L2-resident slot-order
// Wt (16-lane groups read 256B contiguous). A-frags coalesced from global.
// K-loop has zero barriers / zero forced waitcnt drains -> compiler
// software-pipelines loads under MFMA.
__global__ __launch_bounds__(256, 2) void gemm_stream(
    const ushort* __restrict__ A1, const ushort* __restrict__ W1t,
    const ushort* __restrict__ A2, const ushort* __restrict__ W2t,
    const float* __restrict__ bias, ushort* __restrict__ out_bf,
    float* __restrict__ out_f32, int M, int K, int relu)
{
    int tid = threadIdx.x;
    int w = tid >> 6, lane = tid & 63;
    int m_ = lane & 15, koq = lane >> 4;
    int row0 = blockIdx.x * 128;
    int nk = K >> 5;  // 32-k slices

    floatx4 acc[2][16];
#pragma unroll
    for (int i = 0; i < 2; ++i)
#pragma unroll
        for (int f = 0; f < 16; ++f) acc[i][f] = (floatx4){0.f, 0.f, 0.f, 0.f};

    int ra = row0 + w * 32 + m_;      if (ra > M - 1) ra = M - 1;
    int rb = row0 + w * 32 + 16 + m_; if (rb > M - 1) rb = M - 1;

    for (int mm = 0; mm < 2; ++mm) {
        const ushort* __restrict__ A  = mm ? A2 : A1;
        const ushort* __restrict__ Wt = mm ? W2t : W1t;
        const ushort* __restrict__ Aa = &A[(size_t)ra * K + koq * 8];
        const ushort* __restrict__ Ab = &A[(size_t)rb * K + koq * 8];
        // per-lane b base: slot (koq*256 + m_); per g: +8192 ushorts; per fc: +128
        const ushort* __restrict__ Wb = &Wt[(size_t)((koq << 8) + m_) * 8];

        short8 a0 = *(const short8*)&Aa[0];
        short8 a1 = *(const short8*)&Ab[0];
        for (int g = 0; g < nk; ++g) {
            short8 b0[8], b1[8];
#pragma unroll
            for (int j = 0; j < 8; ++j)
                b0[j] = *(const short8*)&Wb[(size_t)g * 8192 + j * 128];
#pragma unroll
            for (int j = 0; j < 8; ++j)
                b1[j] = *(const short8*)&Wb[(size_t)g * 8192 + (8 + j) * 128];
#pragma unroll
            for (int j = 0; j < 8; ++j) {
                acc[0][j] = __builtin_amdgcn_mfma_f32_16x16x32_bf16(a0, b0[j], acc[0][j], 0, 0, 0);
                acc[1][j] = __builtin_amdgcn_mfma_f32_16x16x32_bf16(a1, b0[j], acc[1][j], 0, 0, 0);
            }
            short8 n0, n1;
            if (g + 1 < nk) {  // prefetch next A-frags under second MFMA burst
                n0 = *(const short8*)&Aa[(g + 1) * 32];
                n1 = *(const short8*)&Ab[(g + 1) * 32];
            }
#pragma unroll
            for (int j = 0; j < 8; ++j) {
                acc[0][8 + j] = __builtin_amdgcn_mfma_f32_16x16x32_bf16(a0, b1[j], acc[0][8 + j], 0, 0, 0);
                acc[1][8 + j] = __builtin_amdgcn_mfma_f32_16x16x32_bf16(a1, b1[j], acc[1][8 + j], 0, 0, 0);
            }
            a0 = n0; a1 = n1;
        }
    }

    // epilogue: frag C layout col = m_, row = koq*4 + r
#pragma unroll
    for (int m2 = 0; m2 < 2; ++m2) {
#pragma unroll
        for (int fc = 0; fc < 16; ++fc) {
            int col = fc * 16 + m_;
            float bv = bias[col];
#pragma unroll
            for (int r = 0; r < 4; ++r) {
                int row = row0 + w * 32 + m2 * 16 + koq * 4 + r;
                if (row >= M) continue;
                float v = acc[m2][fc][r] + bv;
                if (relu) v = fmaxf(v, 0.f);
                if (out_f32) out_f32[(size_t)row * 256 + col] = v;
                else         out_bf [(size_t)row * 256 + col] = f2bf(v);
            }
        }
    }
}

// ---------------- launch ----------------

extern "C" void kernel_launch(void* const* d_in, const int* in_sizes, int n_in,
                              void* d_out, int out_size, void* d_ws, size_t ws_size,
                              hipStream_t stream) {
    const float* x    = (const float*)d_in[0];
    const float* W_l0 = (const float*)d_in[1];
    const float* b_l0 = (const float*)d_in[2];
    const float* W_r0 = (const float*)d_in[3];
    const float* W_l1 = (const float*)d_in[4];
    const float* b_l1 = (const float*)d_in[5];
    const float* W_r1 = (const float*)d_in[6];
    const float* W_l2 = (const float*)d_in[7];
    const float* b_l2 = (const float*)d_in[8];
    const float* W_r2 = (const float*)d_in[9];
    const int* esrc   = (const int*)d_in[10];
    const int* edst   = (const int*)d_in[11];
    float* out = (float*)d_out;

    size_t off = 0;
    char* ws = (char*)d_ws;
    auto take = [&](size_t bytes) -> void* {
        void* p = ws + off;
        off += (bytes + 255) & ~(size_t)255;
        return p;
    };
    int*    cnt     = (int*)take((size_t)N_NODES * 4);
    int*    row_ptr = (int*)take((size_t)(N_NODES + 1) * 4);
    int*    col_idx = (int*)take((size_t)N_EDGES * 4);
    int*    bsum    = (int*)take((size_t)SCAN_BLOCKS * 4);
    ushort* xb      = (ushort*)take((size_t)N_NODES * 128 * 2);
    ushort* Wl0t    = (ushort*)take((size_t)256 * 128 * 2);
    ushort* Wr0t    = (ushort*)take((size_t)256 * 128 * 2);
    ushort* Wl1t    = (ushort*)take((size_t)256 * 256 * 2);
    ushort* Wr1t    = (ushort*)take((size_t)256 * 256 * 2);
    ushort* Wl2t    = (ushort*)take((size_t)256 * 256 * 2);
    ushort* Wr2t    = (ushort*)take((size_t)256 * 256 * 2);
    ushort* aggrb   = (ushort*)take((size_t)N_NODES * 256 * 2);
    ushort* ha      = (ushort*)take((size_t)N_NODES * 256 * 2);
    ushort* hb      = (ushort*)take((size_t)N_NODES * 256 * 2);
    (void)ws_size; (void)in_sizes; (void)n_in; (void)out_size;

    // prep: zero cnt, then fused count+convert+transposes
    hipMemsetAsync(cnt, 0, (size_t)N_NODES * 4, stream);
    int total_prep = N_EDGES + N4X + 2 * 32768 + 4 * 65536;
    prep_all<<<(total_prep + 255) / 256, 256, 0, stream>>>(
        edst, cnt, x, xb,
        W_l0, Wl0t, W_r0, Wr0t, W_l1, Wl1t, W_r1, Wr1t, W_l2, Wl2t, W_r2, Wr2t);

    // CSR scan + fill
    scan_partial<<<SCAN_BLOCKS, SCAN_T, 0, stream>>>(cnt, bsum, N_NODES);
    scan_block_sums<<<1, SCAN_T, 0, stream>>>(bsum);
    scan_fill<<<SCAN_BLOCKS, SCAN_T, 0, stream>>>(cnt, bsum, row_ptr, N_NODES);
    int eb = (N_EDGES + 255) / 256;
    fill_csr<<<dim3(eb, FILL_PASSES), 256, 0, stream>>>(esrc, edst, cnt, col_idx);

    dim3 ggrid((N_NODES + 127) / 128, 1);

    // layer 0: 128 -> 256, relu
    aggregate_bf16<<<N_NODES, 64, 0, stream>>>(xb, row_ptr, col_idx, aggrb, 128);
    gemm_stream<<<ggrid, 256, 0, stream>>>(aggrb, Wl0t, xb, Wr0t, b_l0,
                                           ha, nullptr, N_NODES, 128, 1);
    // layer 1: 256 -> 256, relu
    aggregate_bf16<<<N_NODES, 64, 0, stream>>>(ha, row_ptr, col_idx, aggrb, 256);
    gemm_stream<<<ggrid, 256, 0, stream>>>(aggrb, Wl1t, ha, Wr1t, b_l1,
                                           hb, nullptr, N_NODES, 256, 1);
    // layer 2: 256 -> 256, no relu, fp32 out
    aggregate_bf16<<<N_NODES, 64, 0, stream>>>(hb, row_ptr, col_idx, aggrb, 256);
    gemm_stream<<<ggrid, 256, 0, stream>>>(aggrb, Wl2t, hb, Wr2t, b_l2,
                                           nullptr, out, N_NODES, 256, 0);
}

// Round 6
// 788.195 us; speedup vs baseline: 1.1249x; 1.1249x over previous
//
#include <hip/hip_runtime.h>
#include <cstdint>
#include <cstddef>

// SAGE 3-layer GNN, MI355X gfx950 — round 9: FUSED aggregate+GEMM.
// Evidence: every standalone GEMM structure = ~100-115 µs/layer, latency-
// bound (MfmaUtil 9%, Occ 17%) — unfixable in isolation for N=256 skinny
// shape. Aggregate = 114 µs at 49% HBM with MFMA idle. Fusion overlaps the
// two regimes and deletes the aggr HBM round-trip (100 MB/layer):
//   block = 64 nodes, 8 waves. Phase 1: wave w aggregates nodes w*8..w*8+7
//   into swizzled LDS rows (round-5 gather form: 2 edges/instr, 4-deep).
//   Phase 2: wave w computes 16 rows x 128 cols via MFMA; A1 from LDS
//   (XOR-swizzle -> conflict-free ds_read_b128), A2 self-rows from global,
//   B streamed from L2-resident slot-order W. acc[8]=32 AGPR, b[8]=32 VGPR
//   -> <=128 regs -> 16 waves/CU.

#define N_NODES 100000
#define N_EDGES 1600000

#define SCAN_BLOCKS 256
#define SCAN_T 256
#define FILL_PASSES 4

typedef unsigned short ushort;
typedef unsigned int uint;
typedef __attribute__((ext_vector_type(8))) short short8;
typedef __attribute__((ext_vector_type(4))) float floatx4;

#define AS1 __attribute__((address_space(1)))
#define AS3 __attribute__((address_space(3)))

__device__ __forceinline__ float bf2f(ushort h) {
    union { uint u; float f; } c; c.u = ((uint)h) << 16; return c.f;
}
__device__ __forceinline__ ushort f2bf(float f) {
    union { float f; uint u; } c; c.f = f;
    uint u = c.u;
    return (ushort)((u + 0x7FFFu + ((u >> 16) & 1u)) >> 16);  // RTNE
}

// ---------------- fused prep: count_edges + convert_x + 6 W transposes ----
// W [K,256] f32 -> Wt in slot order: elem i = ((q*256 + col)*8 + e),
// k = q*8 + e. A b-frag load reads 16B/lane, 256B-contiguous per 16-lane
// group.

#define N4X (N_NODES * 128 / 4)

__global__ void prep_all(
    const int* __restrict__ dst, int* __restrict__ cnt,
    const float* __restrict__ x, ushort* __restrict__ xb,
    const float* __restrict__ Wl0, ushort* __restrict__ Wl0t,
    const float* __restrict__ Wr0, ushort* __restrict__ Wr0t,
    const float* __restrict__ Wl1, ushort* __restrict__ Wl1t,
    const float* __restrict__ Wr1, ushort* __restrict__ Wr1t,
    const float* __restrict__ Wl2, ushort* __restrict__ Wl2t,
    const float* __restrict__ Wr2, ushort* __restrict__ Wr2t)
{
    int i = blockIdx.x * blockDim.x + threadIdx.x;
    if (i < N_EDGES) { atomicAdd(&cnt[dst[i]], 1); return; }
    i -= N_EDGES;
    if (i < N4X) {
        float4 v = *(const float4*)&x[(size_t)i * 4];
        ushort4 o;
        o.x = f2bf(v.x); o.y = f2bf(v.y); o.z = f2bf(v.z); o.w = f2bf(v.w);
        *(ushort4*)&xb[(size_t)i * 4] = o;
        return;
    }
    i -= N4X;
#define WT2(Wsrc, Wdst, LIM) \
    if (i < (LIM)) { \
        int q = i >> 11, col = (i >> 3) & 255, e = i & 7; \
        Wdst[i] = f2bf(Wsrc[(q * 8 + e) * 256 + col]); \
        return; \
    } \
    i -= (LIM);
    WT2(Wl0, Wl0t, 32768)
    WT2(Wr0, Wr0t, 32768)
    WT2(Wl1, Wl1t, 65536)
    WT2(Wr1, Wr1t, 65536)
    WT2(Wl2, Wl2t, 65536)
    WT2(Wr2, Wr2t, 65536)
#undef WT2
}

// ---------------- CSR scan ----------------

__global__ __launch_bounds__(SCAN_T) void scan_partial(
    const int* __restrict__ cnt, int* __restrict__ bsum, int n)
{
    int chunk = (n + SCAN_BLOCKS - 1) / SCAN_BLOCKS;
    int beg = blockIdx.x * chunk;
    int end = beg + chunk; if (end > n) end = n;
    int t = threadIdx.x;
    int s = 0;
    for (int i = beg + t; i < end; i += SCAN_T) s += cnt[i];
    __shared__ int sh[SCAN_T];
    sh[t] = s;
    __syncthreads();
    for (int off = SCAN_T / 2; off > 0; off >>= 1) {
        if (t < off) sh[t] += sh[t + off];
        __syncthreads();
    }
    if (t == 0) bsum[blockIdx.x] = sh[0];
}

__global__ __launch_bounds__(SCAN_T) void scan_block_sums(int* __restrict__ bsum) {
    int t = threadIdx.x;
    __shared__ int sh[SCAN_T];
    int v = bsum[t];
    sh[t] = v;
    __syncthreads();
    for (int off = 1; off < SCAN_T; off <<= 1) {
        int u = (t >= off) ? sh[t - off] : 0;
        __syncthreads();
        sh[t] += u;
        __syncthreads();
    }
    bsum[t] = sh[t] - v;  // exclusive
}

__global__ __launch_bounds__(SCAN_T) void scan_fill(
    int* __restrict__ cnt, const int* __restrict__ bsum,
    int* __restrict__ row_ptr, int n)
{
    int chunk = (n + SCAN_BLOCKS - 1) / SCAN_BLOCKS;
    int beg = blockIdx.x * chunk;
    int end = beg + chunk; if (end > n) end = n;
    int t = threadIdx.x;
    int per = (chunk + SCAN_T - 1) / SCAN_T;
    int tb = beg + t * per;
    int te = tb + per; if (te > end) te = end;
    int s = 0;
    for (int i = tb; i < te; ++i) s += cnt[i];
    __shared__ int sh[SCAN_T];
    sh[t] = s;
    __syncthreads();
    for (int off = 1; off < SCAN_T; off <<= 1) {
        int u = (t >= off) ? sh[t - off] : 0;
        __syncthreads();
        sh[t] += u;
        __syncthreads();
    }
    int running = bsum[blockIdx.x] + sh[t] - s;
    for (int i = tb; i < te; ++i) {
        int c = cnt[i];
        row_ptr[i] = running;
        cnt[i] = running;  // becomes fill cursor
        running += c;
    }
    if (blockIdx.x == 0 && t == 0) row_ptr[n] = N_EDGES;
}

// 4 dst-range passes: per-pass dirty col_idx region (~1.6MB) stays L2-resident.
__global__ void fill_csr(const int* __restrict__ src, const int* __restrict__ dst,
                         int* __restrict__ cursor, int* __restrict__ col_idx) {
    int i = blockIdx.x * blockDim.x + threadIdx.x;
    if (i >= N_EDGES) return;
    int lo = (int)blockIdx.y * (N_NODES / FILL_PASSES);
    int hi = lo + (N_NODES / FILL_PASSES);
    int d = dst[i];
    if (d >= lo && d < hi) {
        int p = atomicAdd(&cursor[d], 1);
        col_idx[p] = src[i];
    }
}

// ---------------- fused aggregate + dual GEMM (one layer) ----------------
// Block: 512 thr (8 waves), 64 nodes. LDS A-tile 64 x K bf16, XOR-swizzled
// (byte ^= (row&7)<<4) so phase-2 ds_read_b128 across 16 rows is
// conflict-free. Phase 2: wave w -> rows (w>>1)*16.., col-half (w&1)*128.
template <int K>
__global__ __launch_bounds__(512, 4) void sage_fused(
    const ushort* __restrict__ xb,    // [M,K] bf16: gather source AND self rows
    const int* __restrict__ row_ptr, const int* __restrict__ col_idx,
    const ushort* __restrict__ Wlt,   // lin_l, slot-order
    const ushort* __restrict__ Wrt,   // lin_r, slot-order
    const float* __restrict__ bias,
    ushort* __restrict__ out_bf, float* __restrict__ out_f32,
    int M, int relu)
{
    __shared__ __align__(16) ushort Alds[64 * 256];  // 32 KB @ K=256
    char* lb = (char*)Alds;
    int tid = threadIdx.x;
    int w = tid >> 6, lane = tid & 63;
    int half = lane >> 5, li = lane & 31;
    int row0 = blockIdx.x * 64;

    // ---- phase 1: wave w aggregates nodes row0 + w*8 .. +7 ----
    for (int s = 0; s < 8; ++s) {
        int rowL = w * 8 + s;
        int node = row0 + rowL;
        if (node >= M) break;
        int b = row_ptr[node], e = row_ptr[node + 1];
        float dg = (float)(e - b); if (dg < 1.f) dg = 1.f;
        float inv = 1.f / dg;
        int xv = (rowL & 7) << 4;  // swizzle XOR for this row

        if (K == 256) {
            float a[8];
#pragma unroll
            for (int j = 0; j < 8; ++j) a[j] = 0.f;
            const int c = li * 8;  // 16B per lane, 32 lanes = 512B row
            int i = b;
            for (; i + 7 < e; i += 8) {
                int s0 = col_idx[i + half];
                int s1 = col_idx[i + 2 + half];
                int s2 = col_idx[i + 4 + half];
                int s3 = col_idx[i + 6 + half];
                uint4 v0 = *(const uint4*)&xb[(size_t)s0 * 256 + c];
                uint4 v1 = *(const uint4*)&xb[(size_t)s1 * 256 + c];
                uint4 v2 = *(const uint4*)&xb[(size_t)s2 * 256 + c];
                uint4 v3 = *(const uint4*)&xb[(size_t)s3 * 256 + c];
#define ACC4(v) \
                a[0] += bf2f((ushort)(v.x & 0xffff)); a[1] += bf2f((ushort)(v.x >> 16)); \
                a[2] += bf2f((ushort)(v.y & 0xffff)); a[3] += bf2f((ushort)(v.y >> 16)); \
                a[4] += bf2f((ushort)(v.z & 0xffff)); a[5] += bf2f((ushort)(v.z >> 16)); \
                a[6] += bf2f((ushort)(v.w & 0xffff)); a[7] += bf2f((ushort)(v.w >> 16));
                ACC4(v0) ACC4(v1) ACC4(v2) ACC4(v3)
            }
            for (; i + 1 < e; i += 2) {
                int s0 = col_idx[i + half];
                uint4 v0 = *(const uint4*)&xb[(size_t)s0 * 256 + c];
                ACC4(v0)
            }
            if (i < e && half == 0) {
                int s0 = col_idx[i];
                uint4 v0 = *(const uint4*)&xb[(size_t)s0 * 256 + c];
                ACC4(v0)
            }
#undef ACC4
#pragma unroll
            for (int j = 0; j < 8; ++j) a[j] += __shfl(a[j], li + 32);
            if (half == 0) {
                short8 o;
#pragma unroll
                for (int j = 0; j < 8; ++j) o[j] = (short)f2bf(a[j] * inv);
                int byte = (rowL * 512 + li * 16) ^ xv;
                *(short8*)(lb + byte) = o;
            }
        } else {
            float a[4];
#pragma unroll
            for (int j = 0; j < 4; ++j) a[j] = 0.f;
            const int c = li * 4;  // 8B per lane, 32 lanes = 256B row
            int i = b;
            for (; i + 7 < e; i += 8) {
                int s0 = col_idx[i + half];
                int s1 = col_idx[i + 2 + half];
                int s2 = col_idx[i + 4 + half];
                int s3 = col_idx[i + 6 + half];
                uint2 v0 = *(const uint2*)&xb[(size_t)s0 * 128 + c];
                uint2 v1 = *(const uint2*)&xb[(size_t)s1 * 128 + c];
                uint2 v2 = *(const uint2*)&xb[(size_t)s2 * 128 + c];
                uint2 v3 = *(const uint2*)&xb[(size_t)s3 * 128 + c];
#define ACC2(v) \
                a[0] += bf2f((ushort)(v.x & 0xffff)); a[1] += bf2f((ushort)(v.x >> 16)); \
                a[2] += bf2f((ushort)(v.y & 0xffff)); a[3] += bf2f((ushort)(v.y >> 16));
                ACC2(v0) ACC2(v1) ACC2(v2) ACC2(v3)
            }
            for (; i + 1 < e; i += 2) {
                int s0 = col_idx[i + half];
                uint2 v0 = *(const uint2*)&xb[(size_t)s0 * 128 + c];
                ACC2(v0)
            }
            if (i < e && half == 0) {
                int s0 = col_idx[i];
                uint2 v0 = *(const uint2*)&xb[(size_t)s0 * 128 + c];
                ACC2(v0)
            }
#undef ACC2
#pragma unroll
            for (int j = 0; j < 4; ++j) a[j] += __shfl(a[j], li + 32);
            if (half == 0) {
                ushort4 o;
                o.x = f2bf(a[0] * inv); o.y = f2bf(a[1] * inv);
                o.z = f2bf(a[2] * inv); o.w = f2bf(a[3] * inv);
                int byte = (rowL * 256 + li * 8) ^ xv;
                *(ushort4*)(lb + byte) = o;
            }
        }
    }
    __syncthreads();

    // ---- phase 2: GEMM. wave w -> rows (w>>1)*16.., col frags (w&1)*8.. ----
    int m_ = lane & 15, koq = lane >> 4;
    int wg = w >> 1;           // row group 0..3
    int wc = (w & 1) * 8;      // col-frag base (each frag = 16 cols)
    int rowL = wg * 16 + m_;
    int grow = row0 + rowL; if (grow > M - 1) grow = M - 1;
    const int nk = K >> 5;
    int xv = (rowL & 7) << 4;

    floatx4 acc[8];
#pragma unroll
    for (int f = 0; f < 8; ++f) acc[f] = (floatx4){0.f, 0.f, 0.f, 0.f};

    for (int mm = 0; mm < 2; ++mm) {
        const ushort* __restrict__ Wt = mm ? Wrt : Wlt;
        // base slot = koq*256 + wc*16 + m_ ; ushort offset = slot*8
        const ushort* __restrict__ Wb = &Wt[(size_t)((koq << 8) + wc * 16 + m_) * 8];
        const ushort* __restrict__ Ag = &xb[(size_t)grow * K + koq * 8];
#pragma unroll 1
        for (int g = 0; g < nk; ++g) {
            short8 a;
            if (mm == 0) {
                int byte = (rowL * (K * 2) + g * 64 + koq * 16) ^ xv;
                a = *(const short8*)(lb + byte);
            } else {
                a = *(const short8*)&Ag[g * 32];
            }
            short8 b[8];
#pragma unroll
            for (int j = 0; j < 8; ++j)
                b[j] = *(const short8*)&Wb[(size_t)g * 8192 + j * 128];
#pragma unroll
            for (int j = 0; j < 8; ++j)
                acc[j] = __builtin_amdgcn_mfma_f32_16x16x32_bf16(a, b[j], acc[j], 0, 0, 0);
        }
    }

    // epilogue: frag C layout col = m_, row = koq*4 + r
#pragma unroll
    for (int fc = 0; fc < 8; ++fc) {
        int col = (wc + fc) * 16 + m_;
        float bv = bias[col];
#pragma unroll
        for (int r = 0; r < 4; ++r) {
            int row = row0 + wg * 16 + koq * 4 + r;
            if (row >= M) continue;
            float v = acc[fc][r] + bv;
            if (relu) v = fmaxf(v, 0.f);
            if (out_f32) out_f32[(size_t)row * 256 + col] = v;
            else         out_bf [(size_t)row * 256 + col] = f2bf(v);
        }
    }
}

// ---------------- launch ----------------

extern "C" void kernel_launch(void* const* d_in, const int* in_sizes, int n_in,
                              void* d_out, int out_size, void* d_ws, size_t ws_size,
                              hipStream_t stream) {
    const float* x    = (const float*)d_in[0];
    const float* W_l0 = (const float*)d_in[1];
    const float* b_l0 = (const float*)d_in[2];
    const float* W_r0 = (const float*)d_in[3];
    const float* W_l1 = (const float*)d_in[4];
    const float* b_l1 = (const float*)d_in[5];
    const float* W_r1 = (const float*)d_in[6];
    const float* W_l2 = (const float*)d_in[7];
    const float* b_l2 = (const float*)d_in[8];
    const float* W_r2 = (const float*)d_in[9];
    const int* esrc   = (const int*)d_in[10];
    const int* edst   = (const int*)d_in[11];
    float* out = (float*)d_out;

    size_t off = 0;
    char* ws = (char*)d_ws;
    auto take = [&](size_t bytes) -> void* {
        void* p = ws + off;
        off += (bytes + 255) & ~(size_t)255;
        return p;
    };
    int*    cnt     = (int*)take((size_t)N_NODES * 4);
    int*    row_ptr = (int*)take((size_t)(N_NODES + 1) * 4);
    int*    col_idx = (int*)take((size_t)N_EDGES * 4);
    int*    bsum    = (int*)take((size_t)SCAN_BLOCKS * 4);
    ushort* xb      = (ushort*)take((size_t)N_NODES * 128 * 2);
    ushort* Wl0t    = (ushort*)take((size_t)256 * 128 * 2);
    ushort* Wr0t    = (ushort*)take((size_t)256 * 128 * 2);
    ushort* Wl1t    = (ushort*)take((size_t)256 * 256 * 2);
    ushort* Wr1t    = (ushort*)take((size_t)256 * 256 * 2);
    ushort* Wl2t    = (ushort*)take((size_t)256 * 256 * 2);
    ushort* Wr2t    = (ushort*)take((size_t)256 * 256 * 2);
    ushort* ha      = (ushort*)take((size_t)N_NODES * 256 * 2);
    ushort* hb      = (ushort*)take((size_t)N_NODES * 256 * 2);
    (void)ws_size; (void)in_sizes; (void)n_in; (void)out_size;

    // prep: zero cnt, then fused count+convert+transposes
    hipMemsetAsync(cnt, 0, (size_t)N_NODES * 4, stream);
    int total_prep = N_EDGES + N4X + 2 * 32768 + 4 * 65536;
    prep_all<<<(total_prep + 255) / 256, 256, 0, stream>>>(
        edst, cnt, x, xb,
        W_l0, Wl0t, W_r0, Wr0t, W_l1, Wl1t, W_r1, Wr1t, W_l2, Wl2t, W_r2, Wr2t);

    // CSR scan + fill
    scan_partial<<<SCAN_BLOCKS, SCAN_T, 0, stream>>>(cnt, bsum, N_NODES);
    scan_block_sums<<<1, SCAN_T, 0, stream>>>(bsum);
    scan_fill<<<SCAN_BLOCKS, SCAN_T, 0, stream>>>(cnt, bsum, row_ptr, N_NODES);
    int eb = (N_EDGES + 255) / 256;
    fill_csr<<<dim3(eb, FILL_PASSES), 256, 0, stream>>>(esrc, edst, cnt, col_idx);

    int fgrid = (N_NODES + 63) / 64;  // 1563 blocks

    // layer 0: 128 -> 256, relu
    sage_fused<128><<<fgrid, 512, 0, stream>>>(
        xb, row_ptr, col_idx, Wl0t, Wr0t, b_l0, ha, nullptr, N_NODES, 1);
    // layer 1: 256 -> 256, relu
    sage_fused<256><<<fgrid, 512, 0, stream>>>(
        ha, row_ptr, col_idx, Wl1t, Wr1t, b_l1, hb, nullptr, N_NODES, 1);
    // layer 2: 256 -> 256, no relu, fp32 out
    sage_fused<256><<<fgrid, 512, 0, stream>>>(
        hb, row_ptr, col_idx, Wl2t, Wr2t, b_l2, nullptr, out, N_NODES, 0);
}